// Round 5
// baseline (238.008 us; speedup 1.0000x reference)
//
#include <hip/hip_runtime.h>
#include <hip/hip_bf16.h>
#include <math.h>

#define B_    2
#define C_    192
#define H_    96
#define W_    96
#define HW_   (H_ * W_)          // 9216
#define NPIX_ (B_ * HW_)         // 18432
#define G_    12
#define CG_   16
#define KPTS_ 9
#define MLPH_ 384

typedef __attribute__((ext_vector_type(8))) short s16x8;
typedef __attribute__((ext_vector_type(4))) float f32x4;

__device__ __forceinline__ ushort f2b(float f) {
    __hip_bfloat16 h = __float2bfloat16(f);
    return *reinterpret_cast<ushort*>(&h);
}
__device__ __forceinline__ float b2f(ushort u) {
    return __uint_as_float(((uint)u) << 16);
}
__device__ __forceinline__ float b2f_lo(uint u) { return __uint_as_float(u << 16); }
__device__ __forceinline__ float b2f_hi(uint u) { return __uint_as_float(u & 0xffff0000u); }

#if __has_builtin(__builtin_amdgcn_fdot2_f32_bf16)
typedef __attribute__((ext_vector_type(2))) __bf16 bf16x2;
#define HAVE_DOT2BF 1
__device__ __forceinline__ float dot2bf(uint a, uint b, float c) {
    return __builtin_amdgcn_fdot2_f32_bf16(__builtin_bit_cast(bf16x2, a),
                                           __builtin_bit_cast(bf16x2, b), c, false);
}
#else
#define HAVE_DOT2BF 0
#endif

// ---------------------------------------------------------------------------
// pack: q/k/v NCHW fp32 -> channels-last bf16 Xcl[3][NPIX][192]
// ---------------------------------------------------------------------------
__global__ __launch_bounds__(256) void pack_kernel(
    const float* __restrict__ q, const float* __restrict__ k,
    const float* __restrict__ v, ushort* __restrict__ Xcl)
{
    __shared__ ushort sm[64][196];
    const int t   = threadIdx.x;
    const int hw0 = blockIdx.x * 64;
    const int b   = blockIdx.y;
    const int z   = blockIdx.z;
    const float* X = (z == 0) ? q : (z == 1) ? k : v;

    const int hwl = t & 63;
    #pragma unroll 4
    for (int j = 0; j < 48; ++j) {
        const int c = (t >> 6) + j * 4;
        sm[hwl][c] = f2b(X[(b * C_ + c) * HW_ + hw0 + hwl]);
    }
    __syncthreads();
    #pragma unroll
    for (int jj = 0; jj < 12; ++jj) {
        const int idx = t + 256 * jj;        // < 64*48
        const int row = idx / 48, cq = idx - row * 48;
        const int pix = b * HW_ + hw0 + row;
        *(uint2*)&Xcl[((z * NPIX_) + pix) * C_ + cq * 4] = *(uint2*)&sm[row][cq * 4];
    }
}

// ---------------------------------------------------------------------------
// wpack: weights fp32 -> TRANSPOSED bf16 [N][K]
// ---------------------------------------------------------------------------
__global__ __launch_bounds__(256) void wpack_kernel(
    const float* __restrict__ Wq, const float* __restrict__ Wk,
    const float* __restrict__ Wv, const float* __restrict__ W1,
    const float* __restrict__ W2, ushort* __restrict__ Wt)
{
    const int i = blockIdx.x * 256 + threadIdx.x;
    if (i < 110592) {
        const int s = i / 36864, j = i - s * 36864;
        const float* src = (s == 0) ? Wq : (s == 1) ? Wk : Wv;
        const int d = j / 192, c = j - d * 192;
        Wt[i] = f2b(src[c * 192 + d]);
    } else if (i < 184320) {
        const int j = i - 110592, d = j / 192, c = j - d * 192;
        Wt[i] = f2b(W1[c * 384 + d]);
    } else if (i < 258048) {
        const int j = i - 184320, d = j / 384, c = j - d * 384;
        Wt[i] = f2b(W2[c * 192 + d]);
    }
}

// ---------------------------------------------------------------------------
// Register-direct MFMA GEMM (no LDS staging, no barriers in main loop):
//   O[M][N] = A[M][K] * BT[N][K]^T (+ epilogue). All operands L2-resident.
//   BM=128 BN=64, 4 waves (2m x 2n), each wave 64x32; frags straight from
//   global into VGPRs (16B/lane), full K unroll.
//   EPI 0: bias -> bf16 channels-last (z selects q/k/v)
//   EPI 1: gelu(.+bias) -> bf16
//   EPI 2: .+bias+res(bf16) -> NCHW fp32 via LDS transpose
// ---------------------------------------------------------------------------
template<int KK, int EPI>
__global__ __launch_bounds__(256, 2) void gemm_kernel(
    const ushort* __restrict__ A,  const ushort* __restrict__ BT,
    const float* __restrict__ bias0, const float* __restrict__ bias1,
    const float* __restrict__ bias2,
    ushort* __restrict__ Ob,
    const ushort* __restrict__ res, float* __restrict__ Onchw,
    int zAstr, int zBstr, int zOstr)
{
    const int t  = threadIdx.x;
    const int l  = t & 63;
    const int wid = t >> 6;
    const int wm = wid >> 1, wn = wid & 1;
    const int m0 = blockIdx.x * 128;
    const int n0 = blockIdx.y * 64;
    const int z  = blockIdx.z;
    const int Ntot = gridDim.y * 64;

    const ushort* Az = A  + (size_t)z * zAstr;
    const ushort* Bz = BT + (size_t)z * zBstr;
    const float* bias = (z == 0) ? bias0 : (z == 1) ? bias1 : bias2;

    const int lr = l & 15, lc = (l >> 4) * 8;
    const ushort* pa[4];
    #pragma unroll
    for (int f = 0; f < 4; ++f)
        pa[f] = Az + (size_t)(m0 + wm * 64 + f * 16 + lr) * KK + lc;
    const ushort* pb[2];
    #pragma unroll
    for (int g = 0; g < 2; ++g)
        pb[g] = Bz + (size_t)(n0 + wn * 32 + g * 16 + lr) * KK + lc;

    f32x4 acc[4][2] = {};

    #pragma unroll
    for (int ks = 0; ks < KK / 32; ++ks) {
        s16x8 af[4], bf[2];
        #pragma unroll
        for (int f = 0; f < 4; ++f) af[f] = *(const s16x8*)(pa[f] + ks * 32);
        #pragma unroll
        for (int g = 0; g < 2; ++g) bf[g] = *(const s16x8*)(pb[g] + ks * 32);
        #pragma unroll
        for (int f = 0; f < 4; ++f)
            #pragma unroll
            for (int g = 0; g < 2; ++g)
                acc[f][g] = __builtin_amdgcn_mfma_f32_16x16x32_bf16(af[f], bf[g], acc[f][g], 0, 0, 0);
    }

    const int rowg = l >> 4, ncol = l & 15;
    float bv[2];
    #pragma unroll
    for (int g = 0; g < 2; ++g) bv[g] = bias[n0 + wn * 32 + g * 16 + ncol];

    if constexpr (EPI == 0) {
        ushort* O = Ob + (size_t)z * zOstr;
        #pragma unroll
        for (int f = 0; f < 4; ++f)
            #pragma unroll
            for (int g = 0; g < 2; ++g)
                #pragma unroll
                for (int r = 0; r < 4; ++r) {
                    const int m = m0 + wm * 64 + f * 16 + rowg * 4 + r;
                    const int n = n0 + wn * 32 + g * 16 + ncol;
                    O[(size_t)m * Ntot + n] = f2b(acc[f][g][r] + bv[g]);
                }
    } else if constexpr (EPI == 1) {
        #pragma unroll
        for (int f = 0; f < 4; ++f)
            #pragma unroll
            for (int g = 0; g < 2; ++g)
                #pragma unroll
                for (int r = 0; r < 4; ++r) {
                    const int m = m0 + wm * 64 + f * 16 + rowg * 4 + r;
                    const int n = n0 + wn * 32 + g * 16 + ncol;
                    const float x = acc[f][g][r] + bv[g];
                    Ob[(size_t)m * Ntot + n] = f2b(0.5f * x * (1.f + erff(x * 0.70710678118f)));
                }
    } else {
        __shared__ float tsp[64][132];
        #pragma unroll
        for (int f = 0; f < 4; ++f)
            #pragma unroll
            for (int g = 0; g < 2; ++g)
                #pragma unroll
                for (int r = 0; r < 4; ++r) {
                    const int ml = wm * 64 + f * 16 + rowg * 4 + r;
                    const int nl = wn * 32 + g * 16 + ncol;
                    const float rv = b2f(res[(size_t)(m0 + ml) * C_ + n0 + nl]);
                    tsp[nl][ml] = acc[f][g][r] + bv[g] + rv;
                }
        __syncthreads();
        const int b   = m0 / HW_;
        const int hw0 = m0 - b * HW_;
        #pragma unroll
        for (int jj = 0; jj < 8; ++jj) {
            const int i4 = t + 256 * jj;
            const int nn = i4 >> 5, mc = i4 & 31;
            float4 val = *(float4*)&tsp[nn][mc * 4];
            *(float4*)&Onchw[(size_t)b * C_ * HW_ + (size_t)(n0 + nn) * HW_ + hw0 + mc * 4] = val;
        }
    }
}

// ---------------------------------------------------------------------------
// deformable attention v4: 4 lanes per (pixel, group); lane owns 4 channels.
// 36 corner addrs+weights branch-free; ALL V gathers issued into registers
// before the K-pass (latency hidden under score VALU); packed bf16 dot for
// the K-pass when available.
// ---------------------------------------------------------------------------
__global__ __launch_bounds__(256, 2) void deform_attn_kernel(
    const ushort* __restrict__ qp, const ushort* __restrict__ kp,
    const ushort* __restrict__ vp, const float* __restrict__ offset,
    ushort* __restrict__ aob)
{
    const int t   = threadIdx.x;
    const int bid = blockIdx.x;                    // 3456 blocks
    const int xb  = (bid & 7) * 432 + (bid >> 3);  // XCD-chunked swizzle
    const int pair = xb * 64 + (t >> 2);
    const int lane4 = t & 3;
    const int g   = pair % G_;
    const int pix = pair / G_;
    const int b   = pix / HW_;
    const int hw  = pix - b * HW_;
    const int h   = hw / W_;
    const int w   = hw - h * W_;
    const int gc0 = g * CG_ + lane4 * 4;

    // q: 4 channels (packed + unpacked forms)
    uint2 qu = *(const uint2*)(qp + pix * C_ + gc0);
    const float q0 = b2f_lo(qu.x), q1 = b2f_hi(qu.x);
    const float q2 = b2f_lo(qu.y), q3 = b2f_hi(qu.y);

    // offsets: lane l holds points l, l+4, l+8
    float offy[3] = {0.f, 0.f, 0.f}, offx[3] = {0.f, 0.f, 0.f};
    {
        const int obase = (b * (G_ * 2 * KPTS_) + g * (2 * KPTS_)) * HW_ + hw;
        #pragma unroll
        for (int s = 0; s < 3; ++s) {
            const int kk = lane4 + s * 4;
            if (kk < KPTS_) {
                offy[s] = offset[obase + (kk * 2) * HW_];
                offx[s] = offset[obase + (kk * 2 + 1) * HW_];
            }
        }
    }

    // all 36 corner addresses + masked weights, branch-free
    int   addr[KPTS_][4];
    float wgt[KPTS_][4];
    #pragma unroll
    for (int kk = 0; kk < KPTS_; ++kk) {
        const float oy = __shfl(offy[kk >> 2], kk & 3, 4);
        const float ox = __shfl(offx[kk >> 2], kk & 3, 4);
        const float py = (float)(h - 1 + kk / 3) + oy;
        const float px = (float)(w - 1 + kk % 3) + ox;
        const float fy = floorf(py), fx = floorf(px);
        const int   y0 = (int)fy,   x0 = (int)fx;
        const float wy1 = py - fy, wx1 = px - fx;
        const float wy0 = 1.f - wy1, wx0 = 1.f - wx1;

        const float wy0m = ((unsigned)y0       < (unsigned)H_) ? wy0 : 0.f;
        const float wy1m = ((unsigned)(y0 + 1) < (unsigned)H_) ? wy1 : 0.f;
        const float wx0m = ((unsigned)x0       < (unsigned)W_) ? wx0 : 0.f;
        const float wx1m = ((unsigned)(x0 + 1) < (unsigned)W_) ? wx1 : 0.f;
        const int yc0 = min(max(y0, 0), H_ - 1);
        const int yc1 = min(max(y0 + 1, 0), H_ - 1);
        const int xc0 = min(max(x0, 0), W_ - 1);
        const int xc1 = min(max(x0 + 1, 0), W_ - 1);

        addr[kk][0] = (yc0 * W_ + xc0) * C_ + gc0;  wgt[kk][0] = wy0m * wx0m;
        addr[kk][1] = (yc0 * W_ + xc1) * C_ + gc0;  wgt[kk][1] = wy0m * wx1m;
        addr[kk][2] = (yc1 * W_ + xc0) * C_ + gc0;  wgt[kk][2] = wy1m * wx0m;
        addr[kk][3] = (yc1 * W_ + xc1) * C_ + gc0;  wgt[kk][3] = wy1m * wx1m;
    }

    const ushort* kp_b = kp + (size_t)b * HW_ * C_;
    const ushort* vp_b = vp + (size_t)b * HW_ * C_;

    // ---- issue ALL V gathers first: 36 loads in flight under score VALU ----
    uint2 vu[KPTS_][4];
    #pragma unroll
    for (int kk = 0; kk < KPTS_; ++kk)
        #pragma unroll
        for (int c = 0; c < 4; ++c)
            vu[kk][c] = *(const uint2*)(vp_b + addr[kk][c]);

    // ---- K-pass: stream gathers, per-lane partial dots ----
    float score[KPTS_];
    #pragma unroll
    for (int kk = 0; kk < KPTS_; ++kk) {
        float s = 0.f;
        #pragma unroll
        for (int c = 0; c < 4; ++c) {
            const uint2 ku = *(const uint2*)(kp_b + addr[kk][c]);
#if HAVE_DOT2BF
            const float d = dot2bf(ku.y, qu.y, dot2bf(ku.x, qu.x, 0.f));
#else
            float d = q0 * b2f_lo(ku.x);
            d = fmaf(q1, b2f_hi(ku.x), d);
            d = fmaf(q2, b2f_lo(ku.y), d);
            d = fmaf(q3, b2f_hi(ku.y), d);
#endif
            s = fmaf(wgt[kk][c], d, s);
        }
        score[kk] = s;
    }
    // batched cross-lane reduction
    #pragma unroll
    for (int kk = 0; kk < KPTS_; ++kk) {
        float sc = score[kk];
        sc += __shfl_xor(sc, 1, 4);
        sc += __shfl_xor(sc, 2, 4);
        score[kk] = sc * 0.25f;   // hd^-0.5
    }

    // softmax over 9 points
    float m = score[0];
    #pragma unroll
    for (int kk = 1; kk < KPTS_; ++kk) m = fmaxf(m, score[kk]);
    float ssum = 0.f;
    #pragma unroll
    for (int kk = 0; kk < KPTS_; ++kk) { score[kk] = __expf(score[kk] - m); ssum += score[kk]; }
    const float inv = 1.f / ssum;

    // ---- V accumulation from prefetched registers ----
    f32x4 o = {0.f, 0.f, 0.f, 0.f};
    #pragma unroll
    for (int kk = 0; kk < KPTS_; ++kk) {
        const float p = score[kk] * inv;
        #pragma unroll
        for (int c = 0; c < 4; ++c) {
            const float pw = p * wgt[kk][c];
            o[0] = fmaf(pw, b2f_lo(vu[kk][c].x), o[0]);
            o[1] = fmaf(pw, b2f_hi(vu[kk][c].x), o[1]);
            o[2] = fmaf(pw, b2f_lo(vu[kk][c].y), o[2]);
            o[3] = fmaf(pw, b2f_hi(vu[kk][c].y), o[3]);
        }
    }

    uint2 ob;
    ob.x = (uint)f2b(o[0]) | ((uint)f2b(o[1]) << 16);
    ob.y = (uint)f2b(o[2]) | ((uint)f2b(o[3]) << 16);
    *(uint2*)(aob + pix * C_ + gc0) = ob;
}

// ---------------------------------------------------------------------------
extern "C" void kernel_launch(void* const* d_in, const int* in_sizes, int n_in,
                              void* d_out, int out_size, void* d_ws, size_t ws_size,
                              hipStream_t stream)
{
    const float* q      = (const float*)d_in[0];
    const float* k      = (const float*)d_in[1];
    const float* v      = (const float*)d_in[2];
    const float* offset = (const float*)d_in[3];
    const float* Wq     = (const float*)d_in[4];
    const float* bq     = (const float*)d_in[5];
    const float* Wk     = (const float*)d_in[6];
    const float* bk     = (const float*)d_in[7];
    const float* Wv     = (const float*)d_in[8];
    const float* bv     = (const float*)d_in[9];
    const float* W1     = (const float*)d_in[10];
    const float* b1     = (const float*)d_in[11];
    const float* W2     = (const float*)d_in[12];
    const float* b2     = (const float*)d_in[13];

    ushort* Xcl = (ushort*)d_ws;               // [3][NPIX][192] bf16 packed inputs
    ushort* aob = Xcl;                         // alias: dead after proj
    ushort* qkv = Xcl + 3 * NPIX_ * C_;        // [3][NPIX][192] bf16 q/k/v proj
    ushort* Hb  = qkv + 3 * NPIX_ * C_;        // [NPIX][384] bf16
    ushort* Wt  = Hb + (size_t)NPIX_ * MLPH_;  // transposed bf16 weights
    ushort* W1T = Wt + 110592;
    ushort* W2T = Wt + 184320;

    pack_kernel<<<dim3(HW_ / 64, B_, 3), 256, 0, stream>>>(q, k, v, Xcl);
    wpack_kernel<<<1008, 256, 0, stream>>>(Wq, Wk, Wv, W1, W2, Wt);

    // q/k/v projections -> bf16 channels-last
    gemm_kernel<192, 0><<<dim3(NPIX_ / 128, 3, 3), 256, 0, stream>>>(
        Xcl, Wt, bq, bk, bv, qkv, nullptr, nullptr,
        NPIX_ * C_, C_ * C_, NPIX_ * C_);

    deform_attn_kernel<<<NPIX_ * G_ / 64, 256, 0, stream>>>(
        qkv, qkv + NPIX_ * C_, qkv + 2 * NPIX_ * C_, offset, aob);

    // MLP1: H = gelu(aob @ W1 + b1), bf16
    gemm_kernel<192, 1><<<dim3(NPIX_ / 128, 6, 1), 256, 0, stream>>>(
        aob, W1T, b1, b1, b1, Hb, nullptr, nullptr, 0, 0, 0);

    // MLP2: out = aob + (H @ W2 + b2), NCHW fp32
    gemm_kernel<384, 2><<<dim3(NPIX_ / 128, 3, 1), 256, 0, stream>>>(
        Hb, W2T, b2, b2, b2, nullptr, aob, (float*)d_out, 0, 0, 0);
}

// Round 6
// 207.985 us; speedup vs baseline: 1.1444x; 1.1444x over previous
//
#include <hip/hip_runtime.h>
#include <hip/hip_bf16.h>
#include <math.h>

#define B_    2
#define C_    192
#define H_    96
#define W_    96
#define HW_   (H_ * W_)          // 9216
#define NPIX_ (B_ * HW_)         // 18432
#define G_    12
#define CG_   16
#define KPTS_ 9
#define MLPH_ 384
#define OFFCH (G_ * 2 * KPTS_)   // 216

typedef __attribute__((ext_vector_type(8))) short s16x8;
typedef __attribute__((ext_vector_type(4))) float f32x4;

__device__ __forceinline__ ushort f2b(float f) {
    __hip_bfloat16 h = __float2bfloat16(f);
    return *reinterpret_cast<ushort*>(&h);
}
__device__ __forceinline__ float b2f(ushort u) {
    return __uint_as_float(((uint)u) << 16);
}
__device__ __forceinline__ float b2f_lo(uint u) { return __uint_as_float(u << 16); }
__device__ __forceinline__ float b2f_hi(uint u) { return __uint_as_float(u & 0xffff0000u); }

#if __has_builtin(__builtin_amdgcn_fdot2_f32_bf16)
typedef __attribute__((ext_vector_type(2))) __bf16 bf16x2;
#define HAVE_DOT2BF 1
__device__ __forceinline__ float dot2bf(uint a, uint b, float c) {
    return __builtin_amdgcn_fdot2_f32_bf16(__builtin_bit_cast(bf16x2, a),
                                           __builtin_bit_cast(bf16x2, b), c, false);
}
#else
#define HAVE_DOT2BF 0
#endif

#define GLOAD16(gp, lp)                                                          \
    __builtin_amdgcn_global_load_lds(                                            \
        (const __attribute__((address_space(1))) void*)(gp),                     \
        (__attribute__((address_space(3))) void*)(lp), 16, 0, 0)

// ---------------------------------------------------------------------------
// prep (fused): blockIdx.x ranges
//   [0,864)      : pack q/k/v NCHW fp32 -> channels-last bf16 Xcl[3][NPIX][192]
//   [864,1152)   : offset transpose [B][216][HW] -> offT[pix][216] fp32
//   [1152,2160)  : wpack fp32 weights -> transposed bf16 [N][K]
// ---------------------------------------------------------------------------
__global__ __launch_bounds__(256) void prep_kernel(
    const float* __restrict__ q, const float* __restrict__ k,
    const float* __restrict__ v, const float* __restrict__ offset,
    const float* __restrict__ Wq, const float* __restrict__ Wk,
    const float* __restrict__ Wv, const float* __restrict__ W1,
    const float* __restrict__ W2,
    ushort* __restrict__ Xcl, float* __restrict__ offT, ushort* __restrict__ Wt)
{
    __shared__ ushort sm[64][196];
    const int bx = blockIdx.x;
    const int t  = threadIdx.x;

    if (bx < 864) {            // ---- pack ----
        const int z   = bx / 288;
        const int rem = bx - z * 288;
        const int b   = rem / 144;
        const int hw0 = (rem - b * 144) * 64;
        const float* X = (z == 0) ? q : (z == 1) ? k : v;

        const int hwl = t & 63;
        #pragma unroll 4
        for (int j = 0; j < 48; ++j) {
            const int c = (t >> 6) + j * 4;
            sm[hwl][c] = f2b(X[(b * C_ + c) * HW_ + hw0 + hwl]);
        }
        __syncthreads();
        #pragma unroll
        for (int jj = 0; jj < 12; ++jj) {
            const int idx = t + 256 * jj;        // < 64*48
            const int row = idx / 48, cq = idx - row * 48;
            const int pix = b * HW_ + hw0 + row;
            *(uint2*)&Xcl[((z * NPIX_) + pix) * C_ + cq * 4] = *(uint2*)&sm[row][cq * 4];
        }
    } else if (bx < 1152) {    // ---- offset transpose ----
        const int rem = bx - 864;
        const int b   = rem / 144;
        const int hw0 = (rem - b * 144) * 64;
        #pragma unroll
        for (int j = 0; j < 54; ++j) {
            const int i = t + 256 * j;           // < 64*216
            const int pixl = i / OFFCH, p = i - pixl * OFFCH;
            offT[(size_t)(b * HW_ + hw0 + pixl) * OFFCH + p] =
                offset[(size_t)(b * OFFCH + p) * HW_ + hw0 + pixl];
        }
    } else {                   // ---- wpack ----
        const int i = (bx - 1152) * 256 + t;
        if (i < 110592) {
            const int s = i / 36864, j = i - s * 36864;
            const float* src = (s == 0) ? Wq : (s == 1) ? Wk : Wv;
            const int d = j / 192, c = j - d * 192;
            Wt[i] = f2b(src[c * 192 + d]);
        } else if (i < 184320) {
            const int j = i - 110592, d = j / 192, c = j - d * 192;
            Wt[i] = f2b(W1[c * 384 + d]);
        } else if (i < 258048) {
            const int j = i - 184320, d = j / 384, c = j - d * 384;
            Wt[i] = f2b(W2[c * 192 + d]);
        }
    }
}

// ---------------------------------------------------------------------------
// MFMA GEMM (R4 LDS structure): O[M][N] = A[M][K] * BT[N][K]^T (+ epilogue)
//   BM=128 BN=64 BK=64, 4 waves (2m x 2n), 16x16x32 bf16 MFMA, dbuf LDS.
//   LDS chunk swizzle: physical chunk p at row r holds logical chunk p^(r&7).
//   EPI 0: bias -> bf16; z=0 -> qb[pix][192]; z=1/2 -> kvb[pix][g][K16|V16]
//   EPI 1: gelu(.+bias) -> bf16
//   EPI 2: .+bias+res(bf16) -> NCHW fp32 via LDS transpose
// ---------------------------------------------------------------------------
template<int KK>
__device__ __forceinline__ void stage_tiles64(const ushort* Az, const ushort* Bz,
                                              ushort* dst, int t, int m0, int n0, int kt)
{
    #pragma unroll
    for (int j = 0; j < 4; ++j) {
        const int qq = t + 256 * j;
        const int r = qq >> 3, p = qq & 7;
        const int s = p ^ (r & 7);
        GLOAD16(Az + (size_t)(m0 + r) * KK + kt * 64 + s * 8, dst + qq * 8);
    }
    #pragma unroll
    for (int j = 0; j < 2; ++j) {
        const int qq = t + 256 * j;
        const int r = qq >> 3, p = qq & 7;
        const int s = p ^ (r & 7);
        GLOAD16(Bz + (size_t)(n0 + r) * KK + kt * 64 + s * 8, dst + 8192 + qq * 8);
    }
}

template<int KK, int EPI>
__global__ __launch_bounds__(256) void gemm_kernel(
    const ushort* __restrict__ A,  const ushort* __restrict__ BT,
    const float* __restrict__ bias0, const float* __restrict__ bias1,
    const float* __restrict__ bias2,
    ushort* __restrict__ Ob, ushort* __restrict__ Okv,
    const ushort* __restrict__ res, float* __restrict__ Onchw,
    int zAstr, int zBstr)
{
    __shared__ char lds_raw[49152];          // 2 x (A 16KB + B 8KB); EPI2 reuses
    ushort* smem = (ushort*)lds_raw;

    const int t  = threadIdx.x;
    const int l  = t & 63;
    const int wid = t >> 6;
    const int wm = wid >> 1, wn = wid & 1;
    const int m0 = blockIdx.x * 128;
    const int n0 = blockIdx.y * 64;
    const int z  = blockIdx.z;
    const int Ntot = gridDim.y * 64;
    constexpr int NKT = KK / 64;

    const ushort* Az = A  + (size_t)z * zAstr;
    const ushort* Bz = BT + (size_t)z * zBstr;
    const float* bias = (z == 0) ? bias0 : (z == 1) ? bias1 : bias2;

    // fragment LDS offsets (ushort units)
    int aoff[4][2], boff[2][2];
    #pragma unroll
    for (int f = 0; f < 4; ++f) {
        const int r = wm * 64 + f * 16 + (l & 15);
        #pragma unroll
        for (int ks = 0; ks < 2; ++ks) {
            const int c = ks * 4 + (l >> 4);
            aoff[f][ks] = r * 64 + (c ^ (r & 7)) * 8;
        }
    }
    #pragma unroll
    for (int g = 0; g < 2; ++g) {
        const int r = wn * 32 + g * 16 + (l & 15);
        #pragma unroll
        for (int ks = 0; ks < 2; ++ks) {
            const int c = ks * 4 + (l >> 4);
            boff[g][ks] = 8192 + r * 64 + (c ^ (r & 7)) * 8;
        }
    }

    f32x4 acc[4][2] = {};

    stage_tiles64<KK>(Az, Bz, smem, t, m0, n0, 0);
    __syncthreads();

    for (int kt = 0; kt < NKT; ++kt) {
        if (kt + 1 < NKT)
            stage_tiles64<KK>(Az, Bz, smem + ((kt + 1) & 1) * 12288, t, m0, n0, kt + 1);

        const ushort* buf = smem + (kt & 1) * 12288;
        s16x8 af[4][2], bf[2][2];
        #pragma unroll
        for (int f = 0; f < 4; ++f)
            #pragma unroll
            for (int ks = 0; ks < 2; ++ks) af[f][ks] = *(const s16x8*)(buf + aoff[f][ks]);
        #pragma unroll
        for (int g = 0; g < 2; ++g)
            #pragma unroll
            for (int ks = 0; ks < 2; ++ks) bf[g][ks] = *(const s16x8*)(buf + boff[g][ks]);
        #pragma unroll
        for (int ks = 0; ks < 2; ++ks)
            #pragma unroll
            for (int f = 0; f < 4; ++f)
                #pragma unroll
                for (int g = 0; g < 2; ++g)
                    acc[f][g] = __builtin_amdgcn_mfma_f32_16x16x32_bf16(af[f][ks], bf[g][ks], acc[f][g], 0, 0, 0);
        __syncthreads();
    }

    const int rowg = l >> 4, ncol = l & 15;
    float bv[2];
    #pragma unroll
    for (int g = 0; g < 2; ++g) bv[g] = bias[n0 + wn * 32 + g * 16 + ncol];

    if constexpr (EPI == 0) {
        if (z == 0) {
            #pragma unroll
            for (int f = 0; f < 4; ++f)
                #pragma unroll
                for (int g = 0; g < 2; ++g)
                    #pragma unroll
                    for (int r = 0; r < 4; ++r) {
                        const int m = m0 + wm * 64 + f * 16 + rowg * 4 + r;
                        const int n = n0 + wn * 32 + g * 16 + ncol;
                        Ob[(size_t)m * C_ + n] = f2b(acc[f][g][r] + bv[g]);
                    }
        } else {
            const int voff = (z == 2) ? 16 : 0;
            #pragma unroll
            for (int f = 0; f < 4; ++f)
                #pragma unroll
                for (int g = 0; g < 2; ++g) {
                    const int grp = (n0 >> 4) + wn * 2 + g;       // n/16
                    #pragma unroll
                    for (int r = 0; r < 4; ++r) {
                        const int m = m0 + wm * 64 + f * 16 + rowg * 4 + r;
                        Okv[(size_t)m * (2 * C_) + grp * 32 + voff + ncol] =
                            f2b(acc[f][g][r] + bv[g]);
                    }
                }
        }
    } else if constexpr (EPI == 1) {
        #pragma unroll
        for (int f = 0; f < 4; ++f)
            #pragma unroll
            for (int g = 0; g < 2; ++g)
                #pragma unroll
                for (int r = 0; r < 4; ++r) {
                    const int m = m0 + wm * 64 + f * 16 + rowg * 4 + r;
                    const int n = n0 + wn * 32 + g * 16 + ncol;
                    const float x = acc[f][g][r] + bv[g];
                    Ob[(size_t)m * Ntot + n] = f2b(0.5f * x * (1.f + erff(x * 0.70710678118f)));
                }
    } else {
        float* tsp = (float*)lds_raw;   // [64][132]
        #pragma unroll
        for (int f = 0; f < 4; ++f)
            #pragma unroll
            for (int g = 0; g < 2; ++g)
                #pragma unroll
                for (int r = 0; r < 4; ++r) {
                    const int ml = wm * 64 + f * 16 + rowg * 4 + r;
                    const int nl = wn * 32 + g * 16 + ncol;
                    const float rv = b2f(res[(size_t)(m0 + ml) * C_ + n0 + nl]);
                    tsp[nl * 132 + ml] = acc[f][g][r] + bv[g] + rv;
                }
        __syncthreads();
        const int b   = m0 / HW_;
        const int hw0 = m0 - b * HW_;
        #pragma unroll
        for (int jj = 0; jj < 8; ++jj) {
            const int i4 = t + 256 * jj;
            const int nn = i4 >> 5, mc = i4 & 31;
            float4 val = *(float4*)&tsp[nn * 132 + mc * 4];
            *(float4*)&Onchw[(size_t)b * C_ * HW_ + (size_t)(n0 + nn) * HW_ + hw0 + mc * 4] = val;
        }
    }
}

// ---------------------------------------------------------------------------
// deformable attention v5: 4 lanes per (pixel, group); lane owns 4 channels.
// kv block-interleaved [pix][g][K16|V16] -> one 64B sector per corner;
// offsets pre-transposed [pix][216] -> 3 float2 loads; V kept in registers.
// ---------------------------------------------------------------------------
__global__ __launch_bounds__(256, 2) void deform_attn_kernel(
    const ushort* __restrict__ qb, const ushort* __restrict__ kvb,
    const float* __restrict__ offT, ushort* __restrict__ aob)
{
    const int t   = threadIdx.x;
    const int bid = blockIdx.x;                    // 3456 blocks
    const int xb  = (bid & 7) * 432 + (bid >> 3);  // XCD-chunked swizzle
    const int pair = xb * 64 + (t >> 2);
    const int lane4 = t & 3;
    const int g   = pair % G_;
    const int pix = pair / G_;
    const int b   = pix / HW_;
    const int hw  = pix - b * HW_;
    const int h   = hw / W_;
    const int w   = hw - h * W_;
    const int gc0 = g * CG_ + lane4 * 4;

    // q: 4 channels
    uint2 qu = *(const uint2*)(qb + (size_t)pix * C_ + gc0);

    // offsets: lane l holds points l, l+4, l+8 (y,x adjacent after transpose)
    const float* ob_ = offT + (size_t)pix * OFFCH + g * (2 * KPTS_);
    float offy[3] = {0.f, 0.f, 0.f}, offx[3] = {0.f, 0.f, 0.f};
    {
        float2 p0 = *(const float2*)(ob_ + lane4 * 2);
        float2 p1 = *(const float2*)(ob_ + (lane4 + 4) * 2);
        offy[0] = p0.x; offx[0] = p0.y;
        offy[1] = p1.x; offx[1] = p1.y;
        if (lane4 == 0) {
            float2 p2 = *(const float2*)(ob_ + 16);
            offy[2] = p2.x; offx[2] = p2.y;
        }
    }

    // all 36 corner addresses + masked weights, branch-free
    int   addr[KPTS_][4];
    float wgt[KPTS_][4];
    #pragma unroll
    for (int kk = 0; kk < KPTS_; ++kk) {
        const float oy = __shfl(offy[kk >> 2], kk & 3, 4);
        const float ox = __shfl(offx[kk >> 2], kk & 3, 4);
        const float py = (float)(h - 1 + kk / 3) + oy;
        const float px = (float)(w - 1 + kk % 3) + ox;
        const float fy = floorf(py), fx = floorf(px);
        const int   y0 = (int)fy,   x0 = (int)fx;
        const float wy1 = py - fy, wx1 = px - fx;
        const float wy0 = 1.f - wy1, wx0 = 1.f - wx1;

        const float wy0m = ((unsigned)y0       < (unsigned)H_) ? wy0 : 0.f;
        const float wy1m = ((unsigned)(y0 + 1) < (unsigned)H_) ? wy1 : 0.f;
        const float wx0m = ((unsigned)x0       < (unsigned)W_) ? wx0 : 0.f;
        const float wx1m = ((unsigned)(x0 + 1) < (unsigned)W_) ? wx1 : 0.f;
        const int yc0 = min(max(y0, 0), H_ - 1);
        const int yc1 = min(max(y0 + 1, 0), H_ - 1);
        const int xc0 = min(max(x0, 0), W_ - 1);
        const int xc1 = min(max(x0 + 1, 0), W_ - 1);

        // kv element base: pixel*(384) + g*32 + lane4*4 (K); +16 for V
        const int kvbase = g * 32 + lane4 * 4;
        addr[kk][0] = ((b * HW_ + yc0 * W_ + xc0) * (2 * C_)) + kvbase;  wgt[kk][0] = wy0m * wx0m;
        addr[kk][1] = ((b * HW_ + yc0 * W_ + xc1) * (2 * C_)) + kvbase;  wgt[kk][1] = wy0m * wx1m;
        addr[kk][2] = ((b * HW_ + yc1 * W_ + xc0) * (2 * C_)) + kvbase;  wgt[kk][2] = wy1m * wx0m;
        addr[kk][3] = ((b * HW_ + yc1 * W_ + xc1) * (2 * C_)) + kvbase;  wgt[kk][3] = wy1m * wx1m;
    }

    // ---- K-pass: gather K (1 sector/corner), V rides the same line into regs ----
    float score[KPTS_];
    uint2 vu[KPTS_][4];
    #pragma unroll
    for (int kk = 0; kk < KPTS_; ++kk) {
        float s = 0.f;
        #pragma unroll
        for (int c = 0; c < 4; ++c) {
            const uint2 ku = *(const uint2*)(kvb + addr[kk][c]);
            vu[kk][c]      = *(const uint2*)(kvb + addr[kk][c] + 16);
#if HAVE_DOT2BF
            const float d = dot2bf(ku.y, qu.y, dot2bf(ku.x, qu.x, 0.f));
#else
            float d = b2f_lo(qu.x) * b2f_lo(ku.x);
            d = fmaf(b2f_hi(qu.x), b2f_hi(ku.x), d);
            d = fmaf(b2f_lo(qu.y), b2f_lo(ku.y), d);
            d = fmaf(b2f_hi(qu.y), b2f_hi(ku.y), d);
#endif
            s = fmaf(wgt[kk][c], d, s);
        }
        score[kk] = s;
    }
    // batched cross-lane reduction
    #pragma unroll
    for (int kk = 0; kk < KPTS_; ++kk) {
        float sc = score[kk];
        sc += __shfl_xor(sc, 1, 4);
        sc += __shfl_xor(sc, 2, 4);
        score[kk] = sc * 0.25f;   // hd^-0.5
    }

    // softmax over 9 points
    float m = score[0];
    #pragma unroll
    for (int kk = 1; kk < KPTS_; ++kk) m = fmaxf(m, score[kk]);
    float ssum = 0.f;
    #pragma unroll
    for (int kk = 0; kk < KPTS_; ++kk) { score[kk] = __expf(score[kk] - m); ssum += score[kk]; }
    const float inv = 1.f / ssum;

    // ---- V accumulation from registers ----
    f32x4 o = {0.f, 0.f, 0.f, 0.f};
    #pragma unroll
    for (int kk = 0; kk < KPTS_; ++kk) {
        const float p = score[kk] * inv;
        #pragma unroll
        for (int c = 0; c < 4; ++c) {
            const float pw = p * wgt[kk][c];
            o[0] = fmaf(pw, b2f_lo(vu[kk][c].x), o[0]);
            o[1] = fmaf(pw, b2f_hi(vu[kk][c].x), o[1]);
            o[2] = fmaf(pw, b2f_lo(vu[kk][c].y), o[2]);
            o[3] = fmaf(pw, b2f_hi(vu[kk][c].y), o[3]);
        }
    }

    uint2 obv;
    obv.x = (uint)f2b(o[0]) | ((uint)f2b(o[1]) << 16);
    obv.y = (uint)f2b(o[2]) | ((uint)f2b(o[3]) << 16);
    *(uint2*)(aob + (size_t)pix * C_ + gc0) = obv;
}

// ---------------------------------------------------------------------------
extern "C" void kernel_launch(void* const* d_in, const int* in_sizes, int n_in,
                              void* d_out, int out_size, void* d_ws, size_t ws_size,
                              hipStream_t stream)
{
    const float* q      = (const float*)d_in[0];
    const float* k      = (const float*)d_in[1];
    const float* v      = (const float*)d_in[2];
    const float* offset = (const float*)d_in[3];
    const float* Wq     = (const float*)d_in[4];
    const float* bq     = (const float*)d_in[5];
    const float* Wk     = (const float*)d_in[6];
    const float* bk     = (const float*)d_in[7];
    const float* Wv     = (const float*)d_in[8];
    const float* bv     = (const float*)d_in[9];
    const float* W1     = (const float*)d_in[10];
    const float* b1     = (const float*)d_in[11];
    const float* W2     = (const float*)d_in[12];
    const float* b2     = (const float*)d_in[13];

    ushort* ws0 = (ushort*)d_ws;
    ushort* Xcl = ws0;                              // [3][NPIX][192] bf16 packed inputs
    ushort* aob = Xcl;                              // alias: Xcl dead after proj
    ushort* qb  = Xcl + (size_t)3 * NPIX_ * C_;     // [NPIX][192] bf16
    ushort* kvb = qb  + (size_t)NPIX_ * C_;         // [NPIX][12][K16|V16] bf16
    ushort* Hb  = kvb + (size_t)NPIX_ * 2 * C_;     // [NPIX][384] bf16
    ushort* Wt  = Hb  + (size_t)NPIX_ * MLPH_;      // transposed bf16 weights
    ushort* W1T = Wt + 110592;
    ushort* W2T = Wt + 184320;
    float*  offT = (float*)(Wt + 258048);           // [NPIX][216] fp32 (4B-aligned)

    prep_kernel<<<2160, 256, 0, stream>>>(q, k, v, offset, Wq, Wk, Wv, W1, W2,
                                          Xcl, offT, Wt);

    // q/k/v projections -> qb + kv-interleaved kvb
    gemm_kernel<192, 0><<<dim3(NPIX_ / 128, 3, 3), 256, 0, stream>>>(
        Xcl, Wt, bq, bk, bv, qb, kvb, nullptr, nullptr,
        NPIX_ * C_, C_ * C_);

    deform_attn_kernel<<<NPIX_ * G_ / 64, 256, 0, stream>>>(qb, kvb, offT, aob);

    // MLP1: H = gelu(aob @ W1 + b1), bf16
    gemm_kernel<192, 1><<<dim3(NPIX_ / 128, 6, 1), 256, 0, stream>>>(
        aob, W1T, b1, b1, b1, Hb, nullptr, nullptr, nullptr, 0, 0);

    // MLP2: out = aob + (H @ W2 + b2), NCHW fp32
    gemm_kernel<384, 2><<<dim3(NPIX_ / 128, 3, 1), 256, 0, stream>>>(
        Hb, W2T, b2, b2, b2, nullptr, nullptr, aob, (float*)d_out, 0, 0);
}